// Round 5
// baseline (374.053 us; speedup 1.0000x reference)
//
#include <hip/hip_runtime.h>
#include <math.h>

#define BATCH 256
#define M 128        // txt rows
#define NIMG 127     // valid img cols
#define NP 128       // padded img cols
#define D 1024
#define ITERS 50

typedef __attribute__((ext_vector_type(8))) short bf16x8;
typedef __attribute__((ext_vector_type(4))) float floatx4;

// pack two floats to bf16x2 (RNE), bit-level
static __device__ __forceinline__ unsigned pack_bf16x2(float a, float b) {
    unsigned ua = __builtin_bit_cast(unsigned, a);
    unsigned ub = __builtin_bit_cast(unsigned, b);
    ua += 0x7fffu + ((ua >> 16) & 1u);
    ub += 0x7fffu + ((ub >> 16) & 1u);
    return (ua >> 16) | (ub & 0xffff0000u);
}

static __device__ __forceinline__ bf16x8 pack8(float4 lo, float4 hi) {
    union { unsigned u[4]; bf16x8 v; } r;
    r.u[0] = pack_bf16x2(lo.x, lo.y);
    r.u[1] = pack_bf16x2(lo.z, lo.w);
    r.u[2] = pack_bf16x2(hi.x, hi.y);
    r.u[3] = pack_bf16x2(hi.z, hi.w);
    return r.v;
}

static __device__ __forceinline__ float sumsq4(float4 v, float s) {
    return fmaf(v.x, v.x, fmaf(v.y, v.y, fmaf(v.z, v.z, fmaf(v.w, v.w, s))));
}

// DPP row_ror:n add (16-lane rotate) — VALU-pipe reduction
template<int CTRL>
static __device__ __forceinline__ float dpp_add(float v) {
    int s = __builtin_amdgcn_update_dpp(0, __builtin_bit_cast(int, v), CTRL, 0xf, 0xf, true);
    return v + __builtin_bit_cast(float, s);
}
static __device__ __forceinline__ float red16(float v) {
    v = dpp_add<0x121>(v);
    v = dpp_add<0x122>(v);
    v = dpp_add<0x124>(v);
    v = dpp_add<0x128>(v);
    return v;
}

// ---------------- K1: barrier-free direct-from-global MFMA GEMM ----------------
// 256 blocks (1/batch), 512 threads = 8 waves tiled 4(m) x 2(n).
// Wave (g = w&3, h = w>>2): rows g*32..+31, cols h*64..+63.
// A-frag: x row (mbase+tr*16+col), k = quad*8..+7 within each 32-k step.
// No __syncthreads in the K loop -> compiler emits fine-grained vmcnt waits.
__launch_bounds__(512, 2)
__global__ void gemm_a_kernel(const float* __restrict__ xg,
                              const float* __restrict__ yg,
                              const int* __restrict__ xnum,
                              const int* __restrict__ ynum,
                              float* __restrict__ Aout)
{
    __shared__ __align__(16) float sinvx[M];
    __shared__ __align__(16) float sinvy[NP];
    __shared__ __align__(16) float sxmask[M];   // 1.0 if pad
    __shared__ __align__(16) float symask[NP];

    const int b    = blockIdx.x;
    const int t    = threadIdx.x;
    const int lane = t & 63;
    const int w    = t >> 6;
    const int g    = w & 3;      // m-group
    const int h    = w >> 2;     // n-group
    const int mbase = g * 32;
    const int nbase = h * 64;
    const int col  = lane & 15;
    const int quad = lane >> 4;

    const float* xb = xg + (size_t)b * M * D;
    const float* yb = yg + ((size_t)b * 128 + 1) * D;   // object_vec[:,1:]

    if (t < M)  sxmask[t] = (xnum[b * M + t] == 0) ? 1.0f : 0.0f;
    if (t < NP) symask[t] = (t < NIMG && ynum[b * 128 + t + 1] != 0) ? 0.0f : 1.0f;

    // per-lane fragment row pointers (quad picks the k-slice)
    const float* pax[2];
#pragma unroll
    for (int tr = 0; tr < 2; ++tr)
        pax[tr] = xb + (size_t)(mbase + tr * 16 + col) * D + quad * 8;
    const float* pby[4];
#pragma unroll
    for (int tc = 0; tc < 4; ++tc) {
        int r = nbase + tc * 16 + col;
        if (r > NIMG - 1) r = NIMG - 1;   // row 127 clamped (col masked later)
        pby[tc] = yb + (size_t)r * D + quad * 8;
    }

    floatx4 acc[2][4];
#pragma unroll
    for (int a = 0; a < 2; ++a)
#pragma unroll
        for (int c = 0; c < 4; ++c) acc[a][c] = (floatx4)0.0f;

    float ssqx[2] = {0.f, 0.f};
    float ssqy[4] = {0.f, 0.f, 0.f, 0.f};

#pragma unroll 4
    for (int s = 0; s < 32; ++s) {
        const int off = s * 32;   // floats; byte offsets s*128(+16) <= 4000, fit imm
        float4 xa[2][2], ya[4][2];
#pragma unroll
        for (int tr = 0; tr < 2; ++tr) {
            xa[tr][0] = *(const float4*)(pax[tr] + off);
            xa[tr][1] = *(const float4*)(pax[tr] + off + 4);
        }
#pragma unroll
        for (int tc = 0; tc < 4; ++tc) {
            ya[tc][0] = *(const float4*)(pby[tc] + off);
            ya[tc][1] = *(const float4*)(pby[tc] + off + 4);
        }
        if (h == 0) {   // x-norm duty (waves 0..3 cover all 128 rows)
#pragma unroll
            for (int tr = 0; tr < 2; ++tr)
                ssqx[tr] = sumsq4(xa[tr][1], sumsq4(xa[tr][0], ssqx[tr]));
        }
        if (g == 0) {   // y-norm duty (waves 0,4 cover all 128 cols)
#pragma unroll
            for (int tc = 0; tc < 4; ++tc)
                ssqy[tc] = sumsq4(ya[tc][1], sumsq4(ya[tc][0], ssqy[tc]));
        }
        bf16x8 af[2], bf[4];
#pragma unroll
        for (int tr = 0; tr < 2; ++tr) af[tr] = pack8(xa[tr][0], xa[tr][1]);
#pragma unroll
        for (int tc = 0; tc < 4; ++tc) bf[tc] = pack8(ya[tc][0], ya[tc][1]);
#pragma unroll
        for (int tr = 0; tr < 2; ++tr)
#pragma unroll
            for (int tc = 0; tc < 4; ++tc)
                acc[tr][tc] = __builtin_amdgcn_mfma_f32_16x16x32_bf16(
                    af[tr], bf[tc], acc[tr][tc], 0, 0, 0);
    }

    // finalize norms: each lane's ssq covers quad's k-slices; combine 4 quads
    if (h == 0) {
#pragma unroll
        for (int tr = 0; tr < 2; ++tr) {
            float s2 = ssqx[tr];
            s2 += __shfl_xor(s2, 16);
            s2 += __shfl_xor(s2, 32);
            if (quad == 0) sinvx[mbase + tr * 16 + col] = 1.0f / fmaxf(sqrtf(s2), 1e-5f);
        }
    }
    if (g == 0) {
#pragma unroll
        for (int tc = 0; tc < 4; ++tc) {
            float s2 = ssqy[tc];
            s2 += __shfl_xor(s2, 16);
            s2 += __shfl_xor(s2, 32);
            if (quad == 0) sinvy[nbase + tc * 16 + col] = 1.0f / fmaxf(sqrtf(s2), 1e-5f);
        }
    }
    __syncthreads();   // the only barrier

    // epilogue: A = exp(2*cos - 2), masked -> 0  (C/D layout verified R3/R4)
    float* Ab = Aout + (size_t)b * M * NP;
#pragma unroll
    for (int tr = 0; tr < 2; ++tr)
#pragma unroll
        for (int tc = 0; tc < 4; ++tc) {
            const int n = nbase + tc * 16 + col;
            const float ivy_n = sinvy[n];
            const float ymf   = symask[n];
#pragma unroll
            for (int reg = 0; reg < 4; ++reg) {
                const int m = mbase + tr * 16 + quad * 4 + reg;
                const float p = acc[tr][tc][reg] * sinvx[m] * ivy_n;
                const float a = (sxmask[m] + ymf > 0.0f) ? 0.0f : expf(2.0f * p - 2.0f);
                Ab[m * NP + n] = a;
            }
        }
}

// ---------------- K2: 50 IPOT iterations + loss, ONE barrier per iteration ----
// Thread (ti=t>>4, tj=t&15) owns rows 4*ti..+3, cols 8*tj..+7 of Q,A (registers).
// sigma lives entirely in registers (16-lane DPP reduce gives it to all owners);
// delta needs one cross-wave LDS exchange (double-buffered partials).
__launch_bounds__(512, 2)
__global__ void ipot_kernel(const float* __restrict__ Ain,
                            const int* __restrict__ xnum,
                            const int* __restrict__ ynum,
                            float* __restrict__ out)
{
    __shared__ __align__(16) float partCS[2][8 * 128];
    __shared__ unsigned scnt[16];
    __shared__ float swsum[8];

    const int b    = blockIdx.x;
    const int t    = threadIdx.x;
    const int lane = t & 63;
    const int w    = t >> 6;
    const int tj   = t & 15;
    const int i0   = (t >> 4) * 4;
    const int j0   = tj * 8;

    // lengths via ballot (rows/cols indexed by t)
    bool tpad = true, ipad = true;
    if (t < M)  tpad = (xnum[b * M + t] == 0);
    if (t < NP) ipad = !(t < NIMG && ynum[b * 128 + t + 1] != 0);
    unsigned long long bx = __ballot(t < M  && !tpad);
    unsigned long long by = __ballot(t < NP && !ipad);
    if (lane == 0) { scnt[w] = (unsigned)__popcll(bx); scnt[8 + w] = (unsigned)__popcll(by); }
    __syncthreads();
    float xl = 0.f, yl = 0.f;
#pragma unroll
    for (int k = 0; k < 8; ++k) { xl += (float)scnt[k]; yl += (float)scnt[8 + k]; }

    // per-thread masks for owned rows/cols (registers, no LDS)
    float xm[4];
#pragma unroll
    for (int r = 0; r < 4; ++r)
        xm[r] = (xnum[b * M + i0 + r] == 0) ? 1e4f : 0.0f;
    float ym[8];
#pragma unroll
    for (int j = 0; j < 8; ++j) {
        const int jj = j0 + j;
        ym[j] = (jj < NIMG && ynum[b * 128 + jj + 1] != 0) ? 0.0f : 1e4f;
    }

    // sigma0 for owned rows (registers only)
    const float inv_xl = __builtin_amdgcn_rcpf(xl);
    float sg[4];
#pragma unroll
    for (int r = 0; r < 4; ++r) sg[r] = (xm[r] > 0.0f) ? 0.0f : inv_xl;

    // load A (L2/L3-warm from K1); Q0 = A
    const float* Ab = Ain + (size_t)b * M * NP;
    float Af[4][8], Q[4][8];
#pragma unroll
    for (int r = 0; r < 4; ++r) {
        float4 a0 = *(const float4*)(Ab + (size_t)(i0 + r) * NP + j0);
        float4 a1 = *(const float4*)(Ab + (size_t)(i0 + r) * NP + j0 + 4);
        Af[r][0] = a0.x; Af[r][1] = a0.y; Af[r][2] = a0.z; Af[r][3] = a0.w;
        Af[r][4] = a1.x; Af[r][5] = a1.y; Af[r][6] = a1.z; Af[r][7] = a1.w;
#pragma unroll
        for (int j = 0; j < 8; ++j) Q[r][j] = Af[r][j];
    }

    float lp = 0.0f;
    for (int itn = 0; itn < ITERS; ++itn) {
        float* buf = partCS[itn & 1];
        // ---- colsum[j] = sum_i sigma[i] Q[i][j] (local rows, then wave, then LDS) ----
        float cp[8] = {0.f,0.f,0.f,0.f,0.f,0.f,0.f,0.f};
#pragma unroll
        for (int r = 0; r < 4; ++r)
#pragma unroll
            for (int j = 0; j < 8; ++j)
                cp[j] = fmaf(sg[r], Q[r][j], cp[j]);
#pragma unroll
        for (int j = 0; j < 8; ++j) {
            cp[j] += __shfl_xor(cp[j], 16);
            cp[j] += __shfl_xor(cp[j], 32);
        }
        if (lane < 16) {   // tj == lane here; 16 lanes cover 128 cols
            *(float4*)(&buf[w * 128 + lane * 8])     = make_float4(cp[0], cp[1], cp[2], cp[3]);
            *(float4*)(&buf[w * 128 + lane * 8 + 4]) = make_float4(cp[4], cp[5], cp[6], cp[7]);
        }
        __syncthreads();   // the ONE barrier per iteration
        // every thread sums the 8 wave-partials for its own columns
        float4 s0 = make_float4(0.f, 0.f, 0.f, 0.f);
        float4 s1 = make_float4(0.f, 0.f, 0.f, 0.f);
#pragma unroll
        for (int w8 = 0; w8 < 8; ++w8) {
            float4 p0 = *(const float4*)(&buf[w8 * 128 + j0]);
            float4 p1 = *(const float4*)(&buf[w8 * 128 + j0 + 4]);
            s0.x += p0.x; s0.y += p0.y; s0.z += p0.z; s0.w += p0.w;
            s1.x += p1.x; s1.y += p1.y; s1.z += p1.z; s1.w += p1.w;
        }
        float dl[8];
        dl[0] = __builtin_amdgcn_rcpf(fmaf(yl, s0.x, ym[0]));
        dl[1] = __builtin_amdgcn_rcpf(fmaf(yl, s0.y, ym[1]));
        dl[2] = __builtin_amdgcn_rcpf(fmaf(yl, s0.z, ym[2]));
        dl[3] = __builtin_amdgcn_rcpf(fmaf(yl, s0.w, ym[3]));
        dl[4] = __builtin_amdgcn_rcpf(fmaf(yl, s1.x, ym[4]));
        dl[5] = __builtin_amdgcn_rcpf(fmaf(yl, s1.y, ym[5]));
        dl[6] = __builtin_amdgcn_rcpf(fmaf(yl, s1.z, ym[6]));
        dl[7] = __builtin_amdgcn_rcpf(fmaf(yl, s1.w, ym[7]));
        // ---- rowsum[i] = sum_j delta[j] Q[i][j]; 16-lane DPP reduce (VALU pipe) ----
        float rp[4] = {0.f, 0.f, 0.f, 0.f};
#pragma unroll
        for (int r = 0; r < 4; ++r)
#pragma unroll
            for (int j = 0; j < 8; ++j)
                rp[r] = fmaf(dl[j], Q[r][j], rp[r]);
        float sn[4];
#pragma unroll
        for (int r = 0; r < 4; ++r) {
            rp[r] = red16(rp[r]);                       // all 16 owner-lanes get it
            sn[r] = __builtin_amdgcn_rcpf(fmaf(xl, rp[r], xm[r]));
        }
        if (itn < ITERS - 1) {
#pragma unroll
            for (int r = 0; r < 4; ++r) {
                const float f = sn[r];
#pragma unroll
                for (int j = 0; j < 8; ++j)
                    Q[r][j] *= Af[r][j] * dl[j] * f;
            }
        } else {
            // loss = sum C * delta[j] * sigma[i] * Q ; C = -0.5 ln A
#pragma unroll
            for (int r = 0; r < 4; ++r)
#pragma unroll
                for (int j = 0; j < 8; ++j) {
                    const float a = Af[r][j];
                    if (a > 0.0f)
                        lp = fmaf(-0.5f * logf(a) * dl[j] * sn[r], Q[r][j], lp);
                }
        }
#pragma unroll
        for (int r = 0; r < 4; ++r) sg[r] = sn[r];
    }

#pragma unroll
    for (int off = 32; off > 0; off >>= 1) lp += __shfl_down(lp, off);
    if (lane == 0) swsum[w] = lp;
    __syncthreads();
    if (t == 0) {
        float tot = 0.f;
        for (int k = 0; k < 8; ++k) tot += swsum[k];
        atomicAdd(out, 0.01f * tot);
    }
}

extern "C" void kernel_launch(void* const* d_in, const int* in_sizes, int n_in,
                              void* d_out, int out_size, void* d_ws, size_t ws_size,
                              hipStream_t stream) {
    const float* x  = (const float*)d_in[0];
    const float* y  = (const float*)d_in[1];
    const int*   xn = (const int*)d_in[2];
    const int*   yn = (const int*)d_in[3];
    float* out = (float*)d_out;
    float* A   = (float*)d_ws;   // 256*128*128*4 = 16.8 MB

    (void)hipMemsetAsync(out, 0, (size_t)out_size * sizeof(float), stream);
    gemm_a_kernel<<<dim3(BATCH), dim3(512), 0, stream>>>(x, y, xn, yn, A);
    ipot_kernel<<<dim3(BATCH), dim3(512), 0, stream>>>(A, xn, yn, out);
}